// Round 3
// baseline (7259.896 us; speedup 1.0000x reference)
//
#include <hip/hip_runtime.h>
#include <stdint.h>

#define NSAMP 400
#define NC 512

// Raw hw transcendentals (v_exp_f32 = 2^x, v_log_f32 = log2 x), with safe
// fallbacks if the builtin name is unavailable in this toolchain.
#if __has_builtin(__builtin_amdgcn_exp2f)
#define EXP2F(x) __builtin_amdgcn_exp2f(x)
#else
#define EXP2F(x) __expf((x) * 0.6931471805599453f)
#endif
#if __has_builtin(__builtin_amdgcn_logf)
#define LOG2F(x) __builtin_amdgcn_logf(x)
#else
#define LOG2F(x) (__logf(x) * 1.4426950408889634f)
#endif

// ---------------------------------------------------------------------------
// Threefry-2x32, 20 rounds — bit-exact match of jax._src.prng.threefry2x32
// ---------------------------------------------------------------------------
static __device__ __forceinline__ uint32_t rotl32(uint32_t v, int n) {
  return (v << n) | (v >> (32 - n));   // v_alignbit_b32 (1 op) / s_lshl+s_lshr+s_or on SALU
}

static __device__ __forceinline__ void threefry2x32(
    uint32_t k0, uint32_t k1, uint32_t x0, uint32_t x1,
    uint32_t& o0, uint32_t& o1)
{
  const uint32_t ks2 = k0 ^ k1 ^ 0x1BD11BDAu;
  x0 += k0; x1 += k1;

  x0 += x1; x1 = rotl32(x1, 13); x1 ^= x0;
  x0 += x1; x1 = rotl32(x1, 15); x1 ^= x0;
  x0 += x1; x1 = rotl32(x1, 26); x1 ^= x0;
  x0 += x1; x1 = rotl32(x1,  6); x1 ^= x0;
  x0 += k1; x1 += ks2 + 1u;

  x0 += x1; x1 = rotl32(x1, 17); x1 ^= x0;
  x0 += x1; x1 = rotl32(x1, 29); x1 ^= x0;
  x0 += x1; x1 = rotl32(x1, 16); x1 ^= x0;
  x0 += x1; x1 = rotl32(x1, 24); x1 ^= x0;
  x0 += ks2; x1 += k0 + 2u;

  x0 += x1; x1 = rotl32(x1, 13); x1 ^= x0;
  x0 += x1; x1 = rotl32(x1, 15); x1 ^= x0;
  x0 += x1; x1 = rotl32(x1, 26); x1 ^= x0;
  x0 += x1; x1 = rotl32(x1,  6); x1 ^= x0;
  x0 += k0; x1 += k1 + 3u;

  x0 += x1; x1 = rotl32(x1, 17); x1 ^= x0;
  x0 += x1; x1 = rotl32(x1, 29); x1 ^= x0;
  x0 += x1; x1 = rotl32(x1, 16); x1 ^= x0;
  x0 += x1; x1 = rotl32(x1, 24); x1 ^= x0;
  x0 += k1; x1 += ks2 + 4u;

  x0 += x1; x1 = rotl32(x1, 13); x1 ^= x0;
  x0 += x1; x1 = rotl32(x1, 15); x1 ^= x0;
  x0 += x1; x1 = rotl32(x1, 26); x1 ^= x0;
  x0 += x1; x1 = rotl32(x1,  6); x1 ^= x0;
  x0 += ks2; x1 += k0 + 5u;

  o0 = x0; o1 = x1;
}

static __device__ __forceinline__ uint32_t tf_bits(uint32_t k0, uint32_t k1, uint32_t cnt) {
  uint32_t y0, y1;
  threefry2x32(k0, k1, 0u, cnt, y0, y1);
  return y0 ^ y1;   // jax partitionable 32-bit fold
}

// erfinv (Giles/XLA coefficients) on a log2 basis, fused with the exp2:
// returns 2^(p(u)*u*sd2 + m2) where sd2 = sd*sqrt2*log2e, m2 = m*log2e.
static __device__ __forceinline__ float softexp(float u, float L, float sd2, float m2) {
  float p;
  if (L > -7.2134752f) {                    // w = -ln2*L < 5 : central branch
    float w = fmaf(L, -0.69314718f, -2.5f); // (-ln2*L) - 2.5 in one fma
    p =              2.81022636e-08f;
    p = fmaf(p, w,   3.43273939e-07f);
    p = fmaf(p, w,  -3.5233877e-06f);
    p = fmaf(p, w,  -4.39150654e-06f);
    p = fmaf(p, w,   0.00021858087f);
    p = fmaf(p, w,  -0.00125372503f);
    p = fmaf(p, w,  -0.00417768164f);
    p = fmaf(p, w,   0.246640727f);
    p = fmaf(p, w,   1.50140941f);
  } else {                                   // tail, ~0.34%/lane
    float w = __builtin_amdgcn_sqrtf(L * -0.69314718f) - 3.0f;
    p =             -0.000200214257f;
    p = fmaf(p, w,   0.000100950558f);
    p = fmaf(p, w,   0.00134934322f);
    p = fmaf(p, w,  -0.00367342844f);
    p = fmaf(p, w,   0.00573950773f);
    p = fmaf(p, w,  -0.0076224613f);
    p = fmaf(p, w,   0.00943887047f);
    p = fmaf(p, w,   1.00167406f);
    p = fmaf(p, w,   2.83297682f);
  }
  float px = p * u;
  return EXP2F(fmaf(px, sd2, m2));
}

// One wave per row; 8 columns per lane; 4 waves/block.
// waves_per_eu(4,4): pin occupancy target at 4 waves/EU so the allocator may
// use ~128 VGPRs — R1/R2 minimized to 36/28 VGPRs, serializing the 16
// independent threefry chains behind dep-latency.
__global__ __launch_bounds__(256)
__attribute__((amdgpu_waves_per_eu(4, 4)))
void mc_softmax_kernel(const float* __restrict__ mean,
                       const float* __restrict__ var,
                       float* __restrict__ out)
{
  const int lane  = threadIdx.x & 63;
  const int row   = (blockIdx.x << 2) + (threadIdx.x >> 6);
  const int cbase = lane << 2;   // columns cbase..cbase+3 and 256+cbase..

  const float* mr = mean + (size_t)row * NC;
  const float* vr = var  + (size_t)row * NC;

  float m2[8], sd2[8], acc[8];
  {
    const float L2E = 1.4426950408889634f;   // log2(e)
    const float S2L = 2.0402788959f;         // sqrt(2)*log2(e)
    float4 t0 = *(const float4*)(mr + cbase);
    float4 t1 = *(const float4*)(mr + 256 + cbase);
    m2[0] = t0.x * L2E; m2[1] = t0.y * L2E; m2[2] = t0.z * L2E; m2[3] = t0.w * L2E;
    m2[4] = t1.x * L2E; m2[5] = t1.y * L2E; m2[6] = t1.z * L2E; m2[7] = t1.w * L2E;
    float4 v0 = *(const float4*)(vr + cbase);
    float4 v1 = *(const float4*)(vr + 256 + cbase);
    sd2[0] = __builtin_amdgcn_sqrtf(v0.x) * S2L;
    sd2[1] = __builtin_amdgcn_sqrtf(v0.y) * S2L;
    sd2[2] = __builtin_amdgcn_sqrtf(v0.z) * S2L;
    sd2[3] = __builtin_amdgcn_sqrtf(v0.w) * S2L;
    sd2[4] = __builtin_amdgcn_sqrtf(v1.x) * S2L;
    sd2[5] = __builtin_amdgcn_sqrtf(v1.y) * S2L;
    sd2[6] = __builtin_amdgcn_sqrtf(v1.z) * S2L;
    sd2[7] = __builtin_amdgcn_sqrtf(v1.w) * S2L;
  }
#pragma unroll
  for (int j = 0; j < 8; ++j) acc[j] = 0.0f;

  const uint32_t base = (uint32_t)(row * NC + cbase);
  const float lo = -0.99999994f;   // nextafter(-1, 0) in f32

  for (int s = 0; s < NSAMP; s += 2) {
    // Sample keys: key_s = threefry((0,42),(0,s)). Wave-uniform (s is the
    // uniform loop counter) -> scalarized onto the SALU, overlaps VALU free.
    uint32_t a0, a1, b0, b1;
    threefry2x32(0u, 42u, 0u, (uint32_t)s,       a0, a1);
    threefry2x32(0u, 42u, 0u, (uint32_t)(s + 1), b0, b1);

    // ---- Phase 1: branch-free. 16 independent threefry chains in ONE basic
    // block -> scheduler interleaves them at issue rate.
    float uA[8], LA[8], uB[8], LB[8];
#pragma unroll
    for (int j = 0; j < 8; ++j) {
      const uint32_t cnt = base + (uint32_t)(j < 4 ? j : 252 + j);
      {
        uint32_t bits = tf_bits(a0, a1, cnt);
        // (bits>>9)|0x3f800000 in one v_alignbit_b32: (0x7F:bits) >> 9
        float f = __uint_as_float(__builtin_amdgcn_alignbit(0x7Fu, bits, 9u)) - 1.0f;
        float u = fmaf(f, 2.0f, lo);           // max(lo,.) is provably identity
        uA[j] = u;
        LA[j] = LOG2F(fmaf(u, -u, 1.0f));
      }
      {
        uint32_t bits = tf_bits(b0, b1, cnt);
        float f = __uint_as_float(__builtin_amdgcn_alignbit(0x7Fu, bits, 9u)) - 1.0f;
        float u = fmaf(f, 2.0f, lo);
        uB[j] = u;
        LB[j] = LOG2F(fmaf(u, -u, 1.0f));
      }
    }

    // ---- Phase 2: branchy erfinv-poly + exp (small share of total ops).
    float eA[8], eB[8], sumA = 0.0f, sumB = 0.0f;
#pragma unroll
    for (int j = 0; j < 8; ++j) {
      eA[j] = softexp(uA[j], LA[j], sd2[j], m2[j]); sumA += eA[j];
      eB[j] = softexp(uB[j], LB[j], sd2[j], m2[j]); sumB += eB[j];
    }

    // ---- Phase 3: two independent wave reductions (latency overlaps).
#pragma unroll
    for (int off = 32; off >= 1; off >>= 1) {
      sumA += __shfl_xor(sumA, off);
      sumB += __shfl_xor(sumB, off);
    }
    const float invA = __builtin_amdgcn_rcpf(sumA);
    const float invB = __builtin_amdgcn_rcpf(sumB);
#pragma unroll
    for (int j = 0; j < 8; ++j)
      acc[j] = fmaf(eA[j], invA, fmaf(eB[j], invB, acc[j]));
  }

  float* orow = out + (size_t)row * NC;
  const float sc = 1.0f / (float)NSAMP;
  float4 o0, o1;
  o0.x = acc[0] * sc; o0.y = acc[1] * sc; o0.z = acc[2] * sc; o0.w = acc[3] * sc;
  o1.x = acc[4] * sc; o1.y = acc[5] * sc; o1.z = acc[6] * sc; o1.w = acc[7] * sc;
  *(float4*)(orow + cbase)       = o0;
  *(float4*)(orow + 256 + cbase) = o1;
}

extern "C" void kernel_launch(void* const* d_in, const int* in_sizes, int n_in,
                              void* d_out, int out_size, void* d_ws, size_t ws_size,
                              hipStream_t stream) {
  const float* mean = (const float*)d_in[0];
  const float* var  = (const float*)d_in[1];
  float* out        = (float*)d_out;

  const int rows = out_size / NC;        // 16384
  const int blocks = rows / 4;           // 4 rows (waves) per 256-thread block
  mc_softmax_kernel<<<blocks, 256, 0, stream>>>(mean, var, out);
}

// Round 4
// 7256.980 us; speedup vs baseline: 1.0004x; 1.0004x over previous
//
#include <hip/hip_runtime.h>
#include <stdint.h>

#define NSAMP 400
#define NC 512

#if __has_builtin(__builtin_amdgcn_exp2f)
#define EXP2F(x) __builtin_amdgcn_exp2f(x)
#else
#define EXP2F(x) __expf((x) * 0.6931471805599453f)
#endif
#if __has_builtin(__builtin_amdgcn_logf)
#define LOG2F(x) __builtin_amdgcn_logf(x)
#else
#define LOG2F(x) (__logf(x) * 1.4426950408889634f)
#endif

// ---------------------------------------------------------------------------
// Rotate-left as ONE v_alignbit_b32: rotl(v,n) == funnel-shift-right(v:v, 32-n).
// R1-R3 used (v<<n)|(v>>(32-n)); if LLVM misses the rotl idiom inside the
// 20-deep unrolled ARX chain, that's 3 ops/rotate -> +40 ops/element, which
// exactly explains the measured 7.1 ms vs the ~4.0 ms issue floor.
// ---------------------------------------------------------------------------
static __device__ __forceinline__ uint32_t rotl32(uint32_t v, int n) {
  return __builtin_amdgcn_alignbit(v, v, 32u - (uint32_t)n);
}
// Scalar-side rotl (wave-uniform key schedule) — plain form, SALU is free.
static __device__ __forceinline__ uint32_t rotl32_s(uint32_t v, int n) {
  return (v << n) | (v >> (32 - n));
}

#define TF_ROUND(x0, x1, R, ROT) \
  x0 += x1; x1 = ROT(x1, R); x1 ^= x0;

// Full threefry2x32 (generic rot) — used for the wave-uniform per-sample key
// derivation, where operands are uniform and the compiler puts it on the SALU.
static __device__ __forceinline__ void threefry2x32_s(
    uint32_t k0, uint32_t k1, uint32_t x0, uint32_t x1,
    uint32_t& o0, uint32_t& o1)
{
  const uint32_t ks2 = k0 ^ k1 ^ 0x1BD11BDAu;
  x0 += k0; x1 += k1;
  TF_ROUND(x0,x1,13,rotl32_s) TF_ROUND(x0,x1,15,rotl32_s)
  TF_ROUND(x0,x1,26,rotl32_s) TF_ROUND(x0,x1, 6,rotl32_s)
  x0 += k1; x1 += ks2 + 1u;
  TF_ROUND(x0,x1,17,rotl32_s) TF_ROUND(x0,x1,29,rotl32_s)
  TF_ROUND(x0,x1,16,rotl32_s) TF_ROUND(x0,x1,24,rotl32_s)
  x0 += ks2; x1 += k0 + 2u;
  TF_ROUND(x0,x1,13,rotl32_s) TF_ROUND(x0,x1,15,rotl32_s)
  TF_ROUND(x0,x1,26,rotl32_s) TF_ROUND(x0,x1, 6,rotl32_s)
  x0 += k0; x1 += k1 + 3u;
  TF_ROUND(x0,x1,17,rotl32_s) TF_ROUND(x0,x1,29,rotl32_s)
  TF_ROUND(x0,x1,16,rotl32_s) TF_ROUND(x0,x1,24,rotl32_s)
  x0 += k1; x1 += ks2 + 4u;
  TF_ROUND(x0,x1,13,rotl32_s) TF_ROUND(x0,x1,15,rotl32_s)
  TF_ROUND(x0,x1,26,rotl32_s) TF_ROUND(x0,x1, 6,rotl32_s)
  x0 += ks2; x1 += k0 + 5u;
  o0 = x0; o1 = x1;
}

// Vector-side threefry with per-lane counter, alignbit rotates, xor-fold
// output (JAX partitionable 32-bit random_bits). Keys are wave-uniform SGPRs.
static __device__ __forceinline__ uint32_t tf_bits(
    uint32_t k0, uint32_t k1, uint32_t ks2, uint32_t cnt)
{
  uint32_t x0 = k0;            // x0 starts at 0 -> +k0 folds to k0
  uint32_t x1 = cnt + k1;
  TF_ROUND(x0,x1,13,rotl32) TF_ROUND(x0,x1,15,rotl32)
  TF_ROUND(x0,x1,26,rotl32) TF_ROUND(x0,x1, 6,rotl32)
  x0 += k1; x1 += ks2 + 1u;
  TF_ROUND(x0,x1,17,rotl32) TF_ROUND(x0,x1,29,rotl32)
  TF_ROUND(x0,x1,16,rotl32) TF_ROUND(x0,x1,24,rotl32)
  x0 += ks2; x1 += k0 + 2u;
  TF_ROUND(x0,x1,13,rotl32) TF_ROUND(x0,x1,15,rotl32)
  TF_ROUND(x0,x1,26,rotl32) TF_ROUND(x0,x1, 6,rotl32)
  x0 += k0; x1 += k1 + 3u;
  TF_ROUND(x0,x1,17,rotl32) TF_ROUND(x0,x1,29,rotl32)
  TF_ROUND(x0,x1,16,rotl32) TF_ROUND(x0,x1,24,rotl32)
  x0 += k1; x1 += ks2 + 4u;
  TF_ROUND(x0,x1,13,rotl32) TF_ROUND(x0,x1,15,rotl32)
  TF_ROUND(x0,x1,26,rotl32) TF_ROUND(x0,x1, 6,rotl32)
  x0 += ks2; x1 += k0 + 5u;
  return x0 ^ x1;
}

// erfinv (Giles/XLA coefficients) on log2 basis fused with exp2:
// returns 2^(p(u)*u*sd2 + m2), sd2 = sd*sqrt2*log2e, m2 = m*log2e.
static __device__ __forceinline__ float softexp(float u, float L, float sd2, float m2) {
  float p;
  if (L > -7.2134752f) {                    // w = -ln2*L < 5 : central branch
    float w = fmaf(L, -0.69314718f, -2.5f);
    p =              2.81022636e-08f;
    p = fmaf(p, w,   3.43273939e-07f);
    p = fmaf(p, w,  -3.5233877e-06f);
    p = fmaf(p, w,  -4.39150654e-06f);
    p = fmaf(p, w,   0.00021858087f);
    p = fmaf(p, w,  -0.00125372503f);
    p = fmaf(p, w,  -0.00417768164f);
    p = fmaf(p, w,   0.246640727f);
    p = fmaf(p, w,   1.50140941f);
  } else {                                   // tail, ~0.34%/lane
    float w = __builtin_amdgcn_sqrtf(L * -0.69314718f) - 3.0f;
    p =             -0.000200214257f;
    p = fmaf(p, w,   0.000100950558f);
    p = fmaf(p, w,   0.00134934322f);
    p = fmaf(p, w,  -0.00367342844f);
    p = fmaf(p, w,   0.00573950773f);
    p = fmaf(p, w,  -0.0076224613f);
    p = fmaf(p, w,   0.00943887047f);
    p = fmaf(p, w,   1.00167406f);
    p = fmaf(p, w,   2.83297682f);
  }
  float px = p * u;
  return EXP2F(fmaf(px, sd2, m2));
}

// One wave per row; 8 columns per lane; 4 waves/block. No occupancy attrs:
// R1-R3 showed perf is insensitive to occupancy (44-76% all ~7.2ms) -> we are
// VALU-issue-bound; let the compiler pick.
__global__ __launch_bounds__(256)
void mc_softmax_kernel(const float* __restrict__ mean,
                       const float* __restrict__ var,
                       float* __restrict__ out)
{
  const int lane  = threadIdx.x & 63;
  const int row   = (blockIdx.x << 2) + (threadIdx.x >> 6);
  const int cbase = lane << 2;

  const float* mr = mean + (size_t)row * NC;
  const float* vr = var  + (size_t)row * NC;

  float m2[8], sd2[8], acc[8];
  {
    const float L2E = 1.4426950408889634f;   // log2(e)
    const float S2L = 2.0402788959f;         // sqrt(2)*log2(e)
    float4 t0 = *(const float4*)(mr + cbase);
    float4 t1 = *(const float4*)(mr + 256 + cbase);
    m2[0] = t0.x * L2E; m2[1] = t0.y * L2E; m2[2] = t0.z * L2E; m2[3] = t0.w * L2E;
    m2[4] = t1.x * L2E; m2[5] = t1.y * L2E; m2[6] = t1.z * L2E; m2[7] = t1.w * L2E;
    float4 v0 = *(const float4*)(vr + cbase);
    float4 v1 = *(const float4*)(vr + 256 + cbase);
    sd2[0] = __builtin_amdgcn_sqrtf(v0.x) * S2L;
    sd2[1] = __builtin_amdgcn_sqrtf(v0.y) * S2L;
    sd2[2] = __builtin_amdgcn_sqrtf(v0.z) * S2L;
    sd2[3] = __builtin_amdgcn_sqrtf(v0.w) * S2L;
    sd2[4] = __builtin_amdgcn_sqrtf(v1.x) * S2L;
    sd2[5] = __builtin_amdgcn_sqrtf(v1.y) * S2L;
    sd2[6] = __builtin_amdgcn_sqrtf(v1.z) * S2L;
    sd2[7] = __builtin_amdgcn_sqrtf(v1.w) * S2L;
  }
#pragma unroll
  for (int j = 0; j < 8; ++j) acc[j] = 0.0f;

  const uint32_t base = (uint32_t)(row * NC + cbase);
  const float lo = -0.99999994f;   // nextafter(-1, 0) in f32

  for (int s = 0; s < NSAMP; ++s) {
    // key_s = threefry((0,42),(0,s)) — wave-uniform -> SALU (free).
    uint32_t k0, k1;
    threefry2x32_s(0u, 42u, 0u, (uint32_t)s, k0, k1);
    const uint32_t ks2 = k0 ^ k1 ^ 0x1BD11BDAu;

    // Phase 1: 8 independent threefry->u->log chains, branch-free block.
    float u8[8], L8[8];
#pragma unroll
    for (int j = 0; j < 8; ++j) {
      const uint32_t cnt = base + (uint32_t)(j < 4 ? j : 252 + j);
      uint32_t bits = tf_bits(k0, k1, ks2, cnt);
      // (bits>>9)|0x3f800000 in one alignbit: ({0x7F:bits} >> 9)
      float f = __uint_as_float(__builtin_amdgcn_alignbit(0x7Fu, bits, 9u)) - 1.0f;
      float u = fmaf(f, 2.0f, lo);           // max(lo,.) provably identity
      u8[j] = u;
      L8[j] = LOG2F(fmaf(u, -u, 1.0f));
    }

    // Phase 2: branchy erfinv-poly + exp2.
    float e8[8], sum = 0.0f;
#pragma unroll
    for (int j = 0; j < 8; ++j) {
      e8[j] = softexp(u8[j], L8[j], sd2[j], m2[j]);
      sum += e8[j];
    }

    // Phase 3: wave-wide denominator.
#pragma unroll
    for (int off = 32; off >= 1; off >>= 1)
      sum += __shfl_xor(sum, off);
    const float inv = __builtin_amdgcn_rcpf(sum);
#pragma unroll
    for (int j = 0; j < 8; ++j)
      acc[j] = fmaf(e8[j], inv, acc[j]);
  }

  float* orow = out + (size_t)row * NC;
  const float sc = 1.0f / (float)NSAMP;
  float4 o0, o1;
  o0.x = acc[0] * sc; o0.y = acc[1] * sc; o0.z = acc[2] * sc; o0.w = acc[3] * sc;
  o1.x = acc[4] * sc; o1.y = acc[5] * sc; o1.z = acc[6] * sc; o1.w = acc[7] * sc;
  *(float4*)(orow + cbase)       = o0;
  *(float4*)(orow + 256 + cbase) = o1;
}

extern "C" void kernel_launch(void* const* d_in, const int* in_sizes, int n_in,
                              void* d_out, int out_size, void* d_ws, size_t ws_size,
                              hipStream_t stream) {
  const float* mean = (const float*)d_in[0];
  const float* var  = (const float*)d_in[1];
  float* out        = (float*)d_out;

  const int rows = out_size / NC;        // 16384
  const int blocks = rows / 4;           // 4 rows (waves) per 256-thread block
  mc_softmax_kernel<<<blocks, 256, 0, stream>>>(mean, var, out);
}